// Round 4
// baseline (1098.625 us; speedup 1.0000x reference)
//
#include <hip/hip_runtime.h>

#define BB    32
#define CINc  64
#define HHc   32
#define WWc   32
#define COc   64
#define KSc   7
#define GGc   8
#define PADc  3
#define CPGc  8
#define NPIX  (HHc * WWc)     // 1024
#define TILEH 8
#define HALOH (TILEH + 6)     // 14
#define HALOW (WWc + 6)       // 38
#define NPOS  (HALOH * HALOW) // 532

// Fully fused: per block (b, g, 8-row tile):
//  1) compute k,v for the block's 8 group channels over the 14x38 halo tile
//     directly from x (weights are wave-uniform -> s_load), zero-padded LDS
//  2) compute q + qrel per thread (own pixel)
//  3) branch-free 7x7 tap loop: scores from LDS, no-max softmax, attn@v, mask
__global__ __launch_bounds__(256) void fused_kernel(
    const float* __restrict__ x,      // [B][64][32][32]
    const float* __restrict__ wq,     // [64][64]
    const float* __restrict__ wk,
    const float* __restrict__ wv,
    const float* __restrict__ rel_h,  // [32][7]
    const float* __restrict__ rel_w,  // [32][7]
    const float* __restrict__ cv,     // [8]
    float* __restrict__ out)          // [B][64][32][32]
{
    __shared__ float ks[CPGc][HALOH][HALOW];
    __shared__ float vs[CPGc][HALOH][HALOW];

    const int blk  = blockIdx.x;
    const int tile = blk & 3;
    const int g    = (blk >> 2) & 7;
    const int b    = blk >> 5;
    const int o0   = g * CPGc;
    const int tid  = threadIdx.x;

    const int y0 = tile * TILEH - PADc;          // first halo row (global)
    const float* xb = x + (size_t)b * CINc * NPIX;

    // ---------- stage k,v into zero-padded LDS halo ----------
    for (int pi = tid; pi < NPOS; pi += 256) {
        const int r  = pi / HALOW;
        const int cc = pi - r * HALOW;
        const int y  = y0 + r;
        const int xx = cc - PADc;
        const bool valid = (y >= 0) && (y < HHc) && (xx >= 0) && (xx < WWc);
        const int off = valid ? (y * WWc + xx) : 0;   // clamped, safe

        float xv[CINc];
#pragma unroll
        for (int c = 0; c < CINc; ++c)
            xv[c] = xb[c * NPIX + off];

#pragma unroll
        for (int oi = 0; oi < CPGc; ++oi) {
            const float* wkr = wk + (o0 + oi) * CINc;   // uniform -> s_load
            const float* wvr = wv + (o0 + oi) * CINc;
            float ak = 0.f, av = 0.f;
#pragma unroll
            for (int c = 0; c < CINc; ++c) {
                ak = fmaf(xv[c], wkr[c], ak);
                av = fmaf(xv[c], wvr[c], av);
            }
            ks[oi][r][cc] = valid ? ak : 0.f;
            vs[oi][r][cc] = valid ? av : 0.f;
        }
    }

    // ---------- q for own pixel ----------
    const int w  = tid & 31;
    const int lh = tid >> 5;
    const int h  = tile * TILEH + lh;

    float xq[CINc];
#pragma unroll
    for (int c = 0; c < CINc; ++c)
        xq[c] = xb[c * NPIX + h * WWc + w];

    float q[CPGc];
#pragma unroll
    for (int oi = 0; oi < CPGc; ++oi) {
        const float* wqr = wq + (o0 + oi) * CINc;       // uniform -> s_load
        float a = 0.f;
#pragma unroll
        for (int c = 0; c < CINc; ++c)
            a = fmaf(xq[c], wqr[c], a);
        q[oi] = a;
    }

    // qrel[t] = sum_oi q[oi] * rel[oi][t]
    const bool use_h = (g < 4);
    const float* relp = use_h ? (rel_h + o0 * KSc) : (rel_w + (o0 - 32) * KSc);
    float qrel[KSc];
#pragma unroll
    for (int t = 0; t < KSc; ++t) {
        float s = 0.f;
#pragma unroll
        for (int oi = 0; oi < CPGc; ++oi)
            s = fmaf(q[oi], relp[oi * KSc + t], s);
        qrel[t] = s;
    }

    __syncthreads();

    // ---------- scores + no-max softmax ----------
    float e[KSc * KSc];
    float den = 0.f;
#pragma unroll
    for (int ki = 0; ki < KSc; ++ki) {
        float s[KSc];
#pragma unroll
        for (int kj = 0; kj < KSc; ++kj)
            s[kj] = use_h ? qrel[ki] : qrel[kj];
#pragma unroll
        for (int oi = 0; oi < CPGc; ++oi) {
            const float qq = q[oi];
            const float* krow = &ks[oi][lh + ki][w];
#pragma unroll
            for (int kj = 0; kj < KSc; ++kj)
                s[kj] = fmaf(qq, krow[kj], s[kj]);
        }
#pragma unroll
        for (int kj = 0; kj < KSc; ++kj) {
            const float ee = __expf(s[kj]);   // |s| stat-bounded ~40 << 88
            e[ki * KSc + kj] = ee;
            den += ee;
        }
    }

    // ---------- attn @ v ----------
    float acc[CPGc];
#pragma unroll
    for (int oi = 0; oi < CPGc; ++oi) acc[oi] = 0.f;
#pragma unroll
    for (int ki = 0; ki < KSc; ++ki) {
#pragma unroll
        for (int oi = 0; oi < CPGc; ++oi) {
            const float* vrow = &vs[oi][lh + ki][w];
            float a = acc[oi];
#pragma unroll
            for (int kj = 0; kj < KSc; ++kj)
                a = fmaf(e[ki * KSc + kj], vrow[kj], a);
            acc[oi] = a;
        }
    }

    // ---------- adaptive mask + write ----------
    const int  r  = min(h, HHc - 1 - h);
    const int  lo = (h <= HHc - 1 - h) ? r : r + 1;
    const int  hi = HHc - 1 - r;
    const bool in_ring = (w >= lo) && (w <= hi);
    const float cvg = cv[g];
    float om = ((float)r - 15.0f + cvg * 16.0f) * (1.0f / 3.0f) + 1.0f;
    om = fminf(fmaxf(om, 0.0f), 1.0f);
    const float maskv = in_ring ? om : 1.0f;
    const float scale = maskv / den;

    float* ob = out + ((size_t)b * COc + o0) * NPIX + h * WWc + w;
#pragma unroll
    for (int oi = 0; oi < CPGc; ++oi)
        ob[(size_t)oi * NPIX] = acc[oi] * scale;
}

extern "C" void kernel_launch(void* const* d_in, const int* in_sizes, int n_in,
                              void* d_out, int out_size, void* d_ws, size_t ws_size,
                              hipStream_t stream) {
    const float* x     = (const float*)d_in[0];
    const float* wq    = (const float*)d_in[1];
    const float* wk    = (const float*)d_in[2];
    const float* wv    = (const float*)d_in[3];
    const float* rel_h = (const float*)d_in[4];
    const float* rel_w = (const float*)d_in[5];
    const float* cv    = (const float*)d_in[6];
    float* out = (float*)d_out;

    fused_kernel<<<1024, 256, 0, stream>>>(x, wq, wk, wv, rel_h, rel_w, cv, out);
}

// Round 5
// 125.945 us; speedup vs baseline: 8.7230x; 8.7230x over previous
//
#include <hip/hip_runtime.h>

#define BB    32
#define CINc  64
#define HHc   32
#define WWc   32
#define COc   64
#define KSc   7
#define GGc   8
#define PADc  3
#define CPGc  8
#define NPIX  (HHc * WWc)     // 1024
#define TILEH 8
#define HALOH (TILEH + 6)     // 14
#define HALOW (WWc + 6)       // 38
#define NPOS  (HALOH * HALOW) // 532

// Fully fused, register-pressure-shaped:
//  1) k,v for the block's 8 group channels over a 14x38 zero-padded LDS halo,
//     computed from x with channel-chunked accumulation (xv[8] live, not xv[64])
//  2) q + qrel per thread (chunked the same way)
//  3) row-fused tap loop: per ki, scores->exp->den/acc immediately (no e[49])
__global__ __launch_bounds__(256) void fused_kernel(
    const float* __restrict__ x,      // [B][64][32][32]
    const float* __restrict__ wq,     // [64][64]
    const float* __restrict__ wk,
    const float* __restrict__ wv,
    const float* __restrict__ rel_h,  // [32][7]
    const float* __restrict__ rel_w,  // [32][7]
    const float* __restrict__ cv,     // [8]
    float* __restrict__ out)          // [B][64][32][32]
{
    __shared__ float ks[CPGc][HALOH][HALOW];
    __shared__ float vs[CPGc][HALOH][HALOW];

    const int blk  = blockIdx.x;
    const int tile = blk & 3;
    const int g    = (blk >> 2) & 7;
    const int b    = blk >> 5;
    const int o0   = g * CPGc;
    const int tid  = threadIdx.x;

    const int y0 = tile * TILEH - PADc;          // first halo row (global)
    const float* xb = x + (size_t)b * CINc * NPIX;

    // ---------- stage k,v into zero-padded LDS halo ----------
    for (int pi = tid; pi < NPOS; pi += 256) {
        const int r  = pi / HALOW;
        const int cc = pi - r * HALOW;
        const int y  = y0 + r;
        const int xx = cc - PADc;
        const bool valid = (y >= 0) && (y < HHc) && (xx >= 0) && (xx < WWc);
        const int off = valid ? (y * WWc + xx) : 0;   // clamped, safe

        float ak[CPGc], av[CPGc];
#pragma unroll
        for (int oi = 0; oi < CPGc; ++oi) { ak[oi] = 0.f; av[oi] = 0.f; }

        for (int c0 = 0; c0 < CINc; c0 += 8) {
            float xv[8];
#pragma unroll
            for (int j = 0; j < 8; ++j)
                xv[j] = xb[(c0 + j) * NPIX + off];
#pragma unroll
            for (int oi = 0; oi < CPGc; ++oi) {
                const float* wkr = wk + (o0 + oi) * CINc + c0;  // uniform -> s_load
                const float* wvr = wv + (o0 + oi) * CINc + c0;
#pragma unroll
                for (int j = 0; j < 8; ++j) {
                    ak[oi] = fmaf(xv[j], wkr[j], ak[oi]);
                    av[oi] = fmaf(xv[j], wvr[j], av[oi]);
                }
            }
        }
#pragma unroll
        for (int oi = 0; oi < CPGc; ++oi) {
            ks[oi][r][cc] = valid ? ak[oi] : 0.f;
            vs[oi][r][cc] = valid ? av[oi] : 0.f;
        }
    }

    // ---------- q for own pixel (chunked) ----------
    const int w  = tid & 31;
    const int lh = tid >> 5;
    const int h  = tile * TILEH + lh;
    const int poff = h * WWc + w;

    float q[CPGc];
#pragma unroll
    for (int oi = 0; oi < CPGc; ++oi) q[oi] = 0.f;

    for (int c0 = 0; c0 < CINc; c0 += 8) {
        float xv[8];
#pragma unroll
        for (int j = 0; j < 8; ++j)
            xv[j] = xb[(c0 + j) * NPIX + poff];
#pragma unroll
        for (int oi = 0; oi < CPGc; ++oi) {
            const float* wqr = wq + (o0 + oi) * CINc + c0;      // uniform -> s_load
#pragma unroll
            for (int j = 0; j < 8; ++j)
                q[oi] = fmaf(xv[j], wqr[j], q[oi]);
        }
    }

    // qrel[t] = sum_oi q[oi] * rel[oi][t]
    const bool use_h = (g < 4);
    const float* relp = use_h ? (rel_h + o0 * KSc) : (rel_w + (o0 - 32) * KSc);
    float qrel[KSc];
#pragma unroll
    for (int t = 0; t < KSc; ++t) {
        float s = 0.f;
#pragma unroll
        for (int oi = 0; oi < CPGc; ++oi)
            s = fmaf(q[oi], relp[oi * KSc + t], s);
        qrel[t] = s;
    }

    __syncthreads();

    // ---------- row-fused: scores -> exp -> den & attn@v per ki ----------
    float den = 0.f;
    float acc[CPGc];
#pragma unroll
    for (int oi = 0; oi < CPGc; ++oi) acc[oi] = 0.f;

#pragma unroll
    for (int ki = 0; ki < KSc; ++ki) {
        float s[KSc];
#pragma unroll
        for (int kj = 0; kj < KSc; ++kj)
            s[kj] = use_h ? qrel[ki] : qrel[kj];
#pragma unroll
        for (int oi = 0; oi < CPGc; ++oi) {
            const float qq = q[oi];
            const float* krow = &ks[oi][lh + ki][w];
#pragma unroll
            for (int kj = 0; kj < KSc; ++kj)
                s[kj] = fmaf(qq, krow[kj], s[kj]);
        }
        float e[KSc];
#pragma unroll
        for (int kj = 0; kj < KSc; ++kj) {
            e[kj] = __expf(s[kj]);   // |s| stat-bounded ~40 << 88: no-max softmax exact
            den += e[kj];
        }
#pragma unroll
        for (int oi = 0; oi < CPGc; ++oi) {
            const float* vrow = &vs[oi][lh + ki][w];
            float a = acc[oi];
#pragma unroll
            for (int kj = 0; kj < KSc; ++kj)
                a = fmaf(e[kj], vrow[kj], a);
            acc[oi] = a;
        }
    }

    // ---------- adaptive mask + write ----------
    const int  r  = min(h, HHc - 1 - h);
    const int  lo = (h <= HHc - 1 - h) ? r : r + 1;
    const int  hi = HHc - 1 - r;
    const bool in_ring = (w >= lo) && (w <= hi);
    const float cvg = cv[g];
    float om = ((float)r - 15.0f + cvg * 16.0f) * (1.0f / 3.0f) + 1.0f;
    om = fminf(fmaxf(om, 0.0f), 1.0f);
    const float maskv = in_ring ? om : 1.0f;
    const float scale = maskv / den;

    float* ob = out + ((size_t)b * COc + o0) * NPIX + poff;
#pragma unroll
    for (int oi = 0; oi < CPGc; ++oi)
        ob[(size_t)oi * NPIX] = acc[oi] * scale;
}

extern "C" void kernel_launch(void* const* d_in, const int* in_sizes, int n_in,
                              void* d_out, int out_size, void* d_ws, size_t ws_size,
                              hipStream_t stream) {
    const float* x     = (const float*)d_in[0];
    const float* wq    = (const float*)d_in[1];
    const float* wk    = (const float*)d_in[2];
    const float* wv    = (const float*)d_in[3];
    const float* rel_h = (const float*)d_in[4];
    const float* rel_w = (const float*)d_in[5];
    const float* cv    = (const float*)d_in[6];
    float* out = (float*)d_out;

    fused_kernel<<<1024, 256, 0, stream>>>(x, wq, wk, wv, rel_h, rel_w, cv, out);
}

// Round 6
// 124.019 us; speedup vs baseline: 8.8585x; 1.0155x over previous
//
#include <hip/hip_runtime.h>

#define BB    32
#define CINc  64
#define HHc   32
#define WWc   32
#define COc   64
#define KSc   7
#define GGc   8
#define PADc  3
#define CPGc  8
#define NPIX  (HHc * WWc)      // 1024
#define TILEH 16
#define HALOH (TILEH + 6)      // 22
#define HALOW (WWc + 6)        // 38
#define NPOS  (HALOH * HALOW)  // 836
#define NVALID (19 * 32)       // 608 valid (non-pad) halo positions
#define NPAD   (NPOS - NVALID) // 228

// LDS layout: per halo position, 16 floats = k[0..7] | v[0..7], stored as four
// float4 chunks with xor-swizzle (logical chunk j at physical j ^ (pos&3)) so
// that b128 taps across consecutive positions spread over all 32 banks (2-way).
__global__ __launch_bounds__(512) void fused_kernel(
    const float* __restrict__ x,      // [B][64][32][32]
    const float* __restrict__ wq,     // [64][64]
    const float* __restrict__ wk,
    const float* __restrict__ wv,
    const float* __restrict__ rel_h,  // [32][7]
    const float* __restrict__ rel_w,  // [32][7]
    const float* __restrict__ cv,     // [8]
    float* __restrict__ out)          // [B][64][32][32]
{
    __shared__ __attribute__((aligned(16))) float kv[NPOS * 16];  // 53.5 KB

    const int blk  = blockIdx.x;
    const int tile = blk & 1;           // 2 row-tiles of 16
    const int g    = (blk >> 1) & 7;
    const int b    = blk >> 4;
    const int o0   = g * CPGc;
    const int tid  = threadIdx.x;

    const int y0  = tile * TILEH - PADc;       // first halo row (global y)
    const int yv0 = (tile == 0) ? 0 : y0;      // first VALID global y
    const int r0  = yv0 - y0;                  // halo row of first valid row
    const float* xb = x + (size_t)b * CINc * NPIX;

    // ---------- zero-fill pad positions (228 pos x 4 b128) ----------
    if (tid < NPAD) {
        int r, cc;
        if (tid < 114) {                       // 3 fully-invalid rows
            const int rb = (tile == 0) ? 0 : 19;
            r  = rb + tid / 38;
            cc = tid % 38;
        } else {                               // valid rows, pad cols 0-2 & 35-37
            const int t = tid - 114;
            const int c6 = t % 6;
            r  = r0 + t / 6;
            cc = (c6 < 3) ? c6 : (c6 + 32);
        }
        float4* dst = (float4*)(kv + (r * HALOW + cc) * 16);
        const float4 z = {0.f, 0.f, 0.f, 0.f};
        dst[0] = z; dst[1] = z; dst[2] = z; dst[3] = z;
    }

    // ---------- stage k,v for valid positions only ----------
    for (int i = tid; i < NVALID; i += 512) {
        const int row = i >> 5;
        const int xx  = i & 31;
        const int y   = yv0 + row;
        const int r   = r0 + row;
        const float* xp = xb + y * WWc + xx;

        float ak[CPGc], av[CPGc];
#pragma unroll
        for (int oi = 0; oi < CPGc; ++oi) { ak[oi] = 0.f; av[oi] = 0.f; }

        for (int c0 = 0; c0 < CINc; c0 += 8) {
            float xv[8];
#pragma unroll
            for (int j = 0; j < 8; ++j)
                xv[j] = xp[(c0 + j) * NPIX];
#pragma unroll
            for (int oi = 0; oi < CPGc; ++oi) {
                const float* wkr = wk + (o0 + oi) * CINc + c0;  // uniform -> s_load
                const float* wvr = wv + (o0 + oi) * CINc + c0;
#pragma unroll
                for (int j = 0; j < 8; ++j) {
                    ak[oi] = fmaf(xv[j], wkr[j], ak[oi]);
                    av[oi] = fmaf(xv[j], wvr[j], av[oi]);
                }
            }
        }

        const int p  = r * HALOW + (xx + PADc);
        const int sw = p & 3;
        float4* dst = (float4*)(kv + p * 16);
        float4 K0 = {ak[0], ak[1], ak[2], ak[3]};
        float4 K1 = {ak[4], ak[5], ak[6], ak[7]};
        float4 V0 = {av[0], av[1], av[2], av[3]};
        float4 V1 = {av[4], av[5], av[6], av[7]};
        dst[0 ^ sw] = K0; dst[1 ^ sw] = K1; dst[2 ^ sw] = V0; dst[3 ^ sw] = V1;
    }

    // ---------- q for own pixel (chunked) ----------
    const int w  = tid & 31;
    const int lh = tid >> 5;               // 0..15
    const int h  = tile * TILEH + lh;
    const int poff = h * WWc + w;

    float q[CPGc];
#pragma unroll
    for (int oi = 0; oi < CPGc; ++oi) q[oi] = 0.f;

    for (int c0 = 0; c0 < CINc; c0 += 8) {
        float xv[8];
#pragma unroll
        for (int j = 0; j < 8; ++j)
            xv[j] = xb[(c0 + j) * NPIX + poff];
#pragma unroll
        for (int oi = 0; oi < CPGc; ++oi) {
            const float* wqr = wq + (o0 + oi) * CINc + c0;      // uniform -> s_load
#pragma unroll
            for (int j = 0; j < 8; ++j)
                q[oi] = fmaf(xv[j], wqr[j], q[oi]);
        }
    }

    // qrel[t] = sum_oi q[oi] * rel[oi][t]
    const bool use_h = (g < 4);
    const float* relp = use_h ? (rel_h + o0 * KSc) : (rel_w + (o0 - 32) * KSc);
    float qrel[KSc];
#pragma unroll
    for (int t = 0; t < KSc; ++t) {
        float s = 0.f;
#pragma unroll
        for (int oi = 0; oi < CPGc; ++oi)
            s = fmaf(q[oi], relp[oi * KSc + t], s);
        qrel[t] = s;
    }

    __syncthreads();

    // ---------- taps: score -> exp -> den & acc, fully fused per tap ----------
    float den = 0.f;
    float acc[CPGc];
#pragma unroll
    for (int oi = 0; oi < CPGc; ++oi) acc[oi] = 0.f;

#pragma unroll
    for (int ki = 0; ki < KSc; ++ki) {
        const int rbase = (lh + ki) * HALOW + w;
#pragma unroll
        for (int kj = 0; kj < KSc; ++kj) {
            const int p  = rbase + kj;
            const int sw = p & 3;
            const float4* bp = (const float4*)(kv + p * 16);
            const float4 k0 = bp[sw];        // logical chunk 0: k[0..3]
            const float4 k1 = bp[1 ^ sw];    // k[4..7]
            const float4 v0 = bp[2 ^ sw];    // v[0..3]
            const float4 v1 = bp[3 ^ sw];    // v[4..7]

            float s = use_h ? qrel[ki] : qrel[kj];
            s = fmaf(q[0], k0.x, s); s = fmaf(q[1], k0.y, s);
            s = fmaf(q[2], k0.z, s); s = fmaf(q[3], k0.w, s);
            s = fmaf(q[4], k1.x, s); s = fmaf(q[5], k1.y, s);
            s = fmaf(q[6], k1.z, s); s = fmaf(q[7], k1.w, s);

            const float e = __expf(s);   // |s| stat-bounded << 88: no-max softmax
            den += e;
            acc[0] = fmaf(e, v0.x, acc[0]); acc[1] = fmaf(e, v0.y, acc[1]);
            acc[2] = fmaf(e, v0.z, acc[2]); acc[3] = fmaf(e, v0.w, acc[3]);
            acc[4] = fmaf(e, v1.x, acc[4]); acc[5] = fmaf(e, v1.y, acc[5]);
            acc[6] = fmaf(e, v1.z, acc[6]); acc[7] = fmaf(e, v1.w, acc[7]);
        }
    }

    // ---------- adaptive mask + write ----------
    const int  r  = min(h, HHc - 1 - h);
    const int  lo = (h <= HHc - 1 - h) ? r : r + 1;
    const int  hi = HHc - 1 - r;
    const bool in_ring = (w >= lo) && (w <= hi);
    const float cvg = cv[g];
    float om = ((float)r - 15.0f + cvg * 16.0f) * (1.0f / 3.0f) + 1.0f;
    om = fminf(fmaxf(om, 0.0f), 1.0f);
    const float maskv = in_ring ? om : 1.0f;
    const float scale = maskv / den;

    float* ob = out + ((size_t)b * COc + o0) * NPIX + poff;
#pragma unroll
    for (int oi = 0; oi < CPGc; ++oi)
        ob[(size_t)oi * NPIX] = acc[oi] * scale;
}

extern "C" void kernel_launch(void* const* d_in, const int* in_sizes, int n_in,
                              void* d_out, int out_size, void* d_ws, size_t ws_size,
                              hipStream_t stream) {
    const float* x     = (const float*)d_in[0];
    const float* wq    = (const float*)d_in[1];
    const float* wk    = (const float*)d_in[2];
    const float* wv    = (const float*)d_in[3];
    const float* rel_h = (const float*)d_in[4];
    const float* rel_w = (const float*)d_in[5];
    const float* cv    = (const float*)d_in[6];
    float* out = (float*)d_out;

    fused_kernel<<<512, 512, 0, stream>>>(x, wq, wk, wv, rel_h, rel_w, cv, out);
}

// Round 7
// 112.073 us; speedup vs baseline: 9.8028x; 1.1066x over previous
//
#include <hip/hip_runtime.h>

#define BB    32
#define CINc  64
#define HHc   32
#define WWc   32
#define COc   64
#define KSc   7
#define GGc   8
#define PADc  3
#define CPGc  8
#define NPIX  (HHc * WWc)      // 1024
#define TILEH 16
#define HALOH (TILEH + 6)      // 22
#define HALOW (WWc + 6)        // 38
#define NPOS  (HALOH * HALOW)  // 836
#define NVALID (19 * 32)       // 608 valid (non-pad) halo positions
#define NPAD   (NPOS - NVALID) // 228

// LDS layout: 4 planes of float4, plane c = {k[0:4], k[4:8], v[0:4], v[4:8]}
// indexed by halo position. Tap reads are stride-1 float4 across consecutive
// lanes -> conflict-free ds_read_b128 (m134 pattern).
__global__ __launch_bounds__(512) void fused_kernel(
    const float* __restrict__ x,      // [B][64][32][32]
    const float* __restrict__ wq,     // [64][64]
    const float* __restrict__ wk,
    const float* __restrict__ wv,
    const float* __restrict__ rel_h,  // [32][7]
    const float* __restrict__ rel_w,  // [32][7]
    const float* __restrict__ cv,     // [8]
    float* __restrict__ out)          // [B][64][32][32]
{
    __shared__ __attribute__((aligned(16))) float4 kvp[4][NPOS];  // 53.5 KB

    const int blk  = blockIdx.x;
    const int tile = blk & 1;           // 2 row-tiles of 16
    const int g    = (blk >> 1) & 7;
    const int b    = blk >> 4;
    const int o0   = g * CPGc;
    const int tid  = threadIdx.x;

    const int y0  = tile * TILEH - PADc;       // first halo row (global y)
    const int yv0 = (tile == 0) ? 0 : y0;      // first VALID global y
    const int r0  = yv0 - y0;                  // halo row of first valid row
    const float* xb = x + (size_t)b * CINc * NPIX;

    // ---------- zero-fill pad positions ----------
    if (tid < NPAD) {
        int r, cc;
        if (tid < 114) {                       // 3 fully-invalid rows
            const int rb = (tile == 0) ? 0 : 19;
            r  = rb + tid / 38;
            cc = tid % 38;
        } else {                               // valid rows, pad cols 0-2 & 35-37
            const int t = tid - 114;
            const int c6 = t % 6;
            r  = r0 + t / 6;
            cc = (c6 < 3) ? c6 : (c6 + 32);
        }
        const int p = r * HALOW + cc;
        const float4 z = {0.f, 0.f, 0.f, 0.f};
        kvp[0][p] = z; kvp[1][p] = z; kvp[2][p] = z; kvp[3][p] = z;
    }

    // ---------- stage k,v for valid positions only ----------
    for (int i = tid; i < NVALID; i += 512) {
        const int row = i >> 5;
        const int xx  = i & 31;
        const int y   = yv0 + row;
        const int r   = r0 + row;
        const float* xp = xb + y * WWc + xx;

        float ak[CPGc], av[CPGc];
#pragma unroll
        for (int oi = 0; oi < CPGc; ++oi) { ak[oi] = 0.f; av[oi] = 0.f; }

        for (int c0 = 0; c0 < CINc; c0 += 8) {
            float xv[8];
#pragma unroll
            for (int j = 0; j < 8; ++j)
                xv[j] = xp[(c0 + j) * NPIX];
#pragma unroll
            for (int oi = 0; oi < CPGc; ++oi) {
                const float* wkr = wk + (o0 + oi) * CINc + c0;  // uniform -> s_load
                const float* wvr = wv + (o0 + oi) * CINc + c0;
#pragma unroll
                for (int j = 0; j < 8; ++j) {
                    ak[oi] = fmaf(xv[j], wkr[j], ak[oi]);
                    av[oi] = fmaf(xv[j], wvr[j], av[oi]);
                }
            }
        }

        const int p = r * HALOW + (xx + PADc);
        kvp[0][p] = (float4){ak[0], ak[1], ak[2], ak[3]};
        kvp[1][p] = (float4){ak[4], ak[5], ak[6], ak[7]};
        kvp[2][p] = (float4){av[0], av[1], av[2], av[3]};
        kvp[3][p] = (float4){av[4], av[5], av[6], av[7]};
    }

    // ---------- q for own pixel (chunked) ----------
    const int w  = tid & 31;
    const int lh = tid >> 5;               // 0..15
    const int h  = tile * TILEH + lh;
    const int poff = h * WWc + w;

    float q[CPGc];
#pragma unroll
    for (int oi = 0; oi < CPGc; ++oi) q[oi] = 0.f;

    for (int c0 = 0; c0 < CINc; c0 += 8) {
        float xv[8];
#pragma unroll
        for (int j = 0; j < 8; ++j)
            xv[j] = xb[(c0 + j) * NPIX + poff];
#pragma unroll
        for (int oi = 0; oi < CPGc; ++oi) {
            const float* wqr = wq + (o0 + oi) * CINc + c0;      // uniform -> s_load
#pragma unroll
            for (int j = 0; j < 8; ++j)
                q[oi] = fmaf(xv[j], wqr[j], q[oi]);
        }
    }

    // qrel[t] = sum_oi q[oi] * rel[oi][t]
    const bool use_h = (g < 4);
    const float* relp = use_h ? (rel_h + o0 * KSc) : (rel_w + (o0 - 32) * KSc);
    float qrel[KSc];
#pragma unroll
    for (int t = 0; t < KSc; ++t) {
        float s = 0.f;
#pragma unroll
        for (int oi = 0; oi < CPGc; ++oi)
            s = fmaf(q[oi], relp[oi * KSc + t], s);
        qrel[t] = s;
    }

    __syncthreads();

    // ---------- taps: score -> exp -> den & acc, fully fused per tap ----------
    float den = 0.f;
    float acc[CPGc];
#pragma unroll
    for (int oi = 0; oi < CPGc; ++oi) acc[oi] = 0.f;

#pragma unroll
    for (int ki = 0; ki < KSc; ++ki) {
        const int rbase = (lh + ki) * HALOW + w;
#pragma unroll
        for (int kj = 0; kj < KSc; ++kj) {
            const int p = rbase + kj;
            const float4 k0 = kvp[0][p];
            const float4 k1 = kvp[1][p];
            const float4 v0 = kvp[2][p];
            const float4 v1 = kvp[3][p];

            float s = use_h ? qrel[ki] : qrel[kj];
            s = fmaf(q[0], k0.x, s); s = fmaf(q[1], k0.y, s);
            s = fmaf(q[2], k0.z, s); s = fmaf(q[3], k0.w, s);
            s = fmaf(q[4], k1.x, s); s = fmaf(q[5], k1.y, s);
            s = fmaf(q[6], k1.z, s); s = fmaf(q[7], k1.w, s);

            const float e = __expf(s);   // |s| stat-bounded << 88: no-max softmax
            den += e;
            acc[0] = fmaf(e, v0.x, acc[0]); acc[1] = fmaf(e, v0.y, acc[1]);
            acc[2] = fmaf(e, v0.z, acc[2]); acc[3] = fmaf(e, v0.w, acc[3]);
            acc[4] = fmaf(e, v1.x, acc[4]); acc[5] = fmaf(e, v1.y, acc[5]);
            acc[6] = fmaf(e, v1.z, acc[6]); acc[7] = fmaf(e, v1.w, acc[7]);
        }
    }

    // ---------- adaptive mask + write ----------
    const int  r  = min(h, HHc - 1 - h);
    const int  lo = (h <= HHc - 1 - h) ? r : r + 1;
    const int  hi = HHc - 1 - r;
    const bool in_ring = (w >= lo) && (w <= hi);
    const float cvg = cv[g];
    float om = ((float)r - 15.0f + cvg * 16.0f) * (1.0f / 3.0f) + 1.0f;
    om = fminf(fmaxf(om, 0.0f), 1.0f);
    const float maskv = in_ring ? om : 1.0f;
    const float scale = maskv / den;

    float* ob = out + ((size_t)b * COc + o0) * NPIX + poff;
#pragma unroll
    for (int oi = 0; oi < CPGc; ++oi)
        ob[(size_t)oi * NPIX] = acc[oi] * scale;
}

extern "C" void kernel_launch(void* const* d_in, const int* in_sizes, int n_in,
                              void* d_out, int out_size, void* d_ws, size_t ws_size,
                              hipStream_t stream) {
    const float* x     = (const float*)d_in[0];
    const float* wq    = (const float*)d_in[1];
    const float* wk    = (const float*)d_in[2];
    const float* wv    = (const float*)d_in[3];
    const float* rel_h = (const float*)d_in[4];
    const float* rel_w = (const float*)d_in[5];
    const float* cv    = (const float*)d_in[6];
    float* out = (float*)d_out;

    fused_kernel<<<512, 512, 0, stream>>>(x, wq, wk, wv, rel_h, rel_w, cv, out);
}